// Round 1
// baseline (1014.397 us; speedup 1.0000x reference)
//
#include <hip/hip_runtime.h>

#define CIN 64
#define COUT 128

// ---------------------------------------------------------------------------
// Conv: for each (k, entry): out[cout_idx[k][e]] += feats[cin_idx[k][e]] @ W_conv[k]
// Weights held in VGPRs (64 per thread, one channel per lane per half-wave-pair).
// Feature row address is wave-uniform -> scalar loads feed v_fma as SGPR operand.
// ---------------------------------------------------------------------------
__global__ __launch_bounds__(256) void conv_scatter_kernel(
    const float* __restrict__ feats,
    const float* __restrict__ Wc,
    const int* __restrict__ cin_idx,
    const int* __restrict__ cout_idx,
    float* __restrict__ out,
    int N, int P)
{
    const int k = blockIdx.y;
    const float* __restrict__ Wk = Wc + (size_t)k * CIN * COUT;
    const int t    = threadIdx.x;
    const int lane = t & 63;
    const int wv   = t >> 6;              // 0..3
    const int ch   = ((wv & 1) << 6) | lane;  // 0..127
    const int rg   = wv >> 1;             // row-stream within block (0/1)

    float w[CIN];
#pragma unroll
    for (int i = 0; i < CIN; ++i) w[i] = Wk[i * COUT + ch];

    const int* __restrict__ cik = cin_idx  + (size_t)k * P;
    const int* __restrict__ cok = cout_idx + (size_t)k * P;

    const int stream_id = blockIdx.x * 2 + rg;
    const int nstreams  = gridDim.x * 2;

    for (int e = stream_id; e < P; e += nstreams) {
        const int ii = cik[e];
        if (ii >= N) continue;            // padding entry (uniform branch)
        const int oo = cok[e];
        const float* __restrict__ f = feats + (size_t)ii * CIN;
        float a0 = 0.f, a1 = 0.f, a2 = 0.f, a3 = 0.f;
#pragma unroll
        for (int i = 0; i < CIN; i += 4) {
            a0 = fmaf(f[i + 0], w[i + 0], a0);
            a1 = fmaf(f[i + 1], w[i + 1], a1);
            a2 = fmaf(f[i + 2], w[i + 2], a2);
            a3 = fmaf(f[i + 3], w[i + 3], a3);
        }
        const float acc = (a0 + a1) + (a2 + a3);
        atomicAdd(&out[(size_t)oo * COUT + ch], acc);
    }
}

// ---------------------------------------------------------------------------
// Skip path: G[e] = feats[sin_idx[e]] @ W_skip ; per-channel sum/sumsq; inv map.
// ---------------------------------------------------------------------------
__global__ __launch_bounds__(256) void skip_kernel(
    const float* __restrict__ feats,
    const float* __restrict__ Ws,
    const int* __restrict__ sin_idx,
    const int* __restrict__ sout_idx,
    float* __restrict__ G,
    int* __restrict__ inv_skip,
    float* __restrict__ skS,
    float* __restrict__ skQ,
    int Ls)
{
    const int t    = threadIdx.x;
    const int lane = t & 63;
    const int wv   = t >> 6;
    const int ch   = ((wv & 1) << 6) | lane;
    const int rg   = wv >> 1;

    float w[CIN];
#pragma unroll
    for (int i = 0; i < CIN; ++i) w[i] = Ws[i * COUT + ch];

    const int stream_id = blockIdx.x * 2 + rg;
    const int nstreams  = gridDim.x * 2;

    float s1 = 0.f, s2 = 0.f;
    for (int e = stream_id; e < Ls; e += nstreams) {
        const int ii = sin_idx[e];
        const int oo = sout_idx[e];
        const float* __restrict__ f = feats + (size_t)ii * CIN;
        float a0 = 0.f, a1 = 0.f, a2 = 0.f, a3 = 0.f;
#pragma unroll
        for (int i = 0; i < CIN; i += 4) {
            a0 = fmaf(f[i + 0], w[i + 0], a0);
            a1 = fmaf(f[i + 1], w[i + 1], a1);
            a2 = fmaf(f[i + 2], w[i + 2], a2);
            a3 = fmaf(f[i + 3], w[i + 3], a3);
        }
        const float acc = (a0 + a1) + (a2 + a3);
        G[(size_t)e * COUT + ch] = acc;
        s1 += acc;
        s2 += acc * acc;
        if (ch == 0) inv_skip[oo] = e;
    }
    atomicAdd(&skS[ch], s1);
    atomicAdd(&skQ[ch], s2);
}

// ---------------------------------------------------------------------------
// Reduce raw accum: per-channel per-batch sums + sumsq + batch counts.
// ---------------------------------------------------------------------------
__global__ __launch_bounds__(256) void reduce_kernel(
    const float* __restrict__ out,
    const int* __restrict__ batch_of_out,
    float* __restrict__ S0, float* __restrict__ S1, float* __restrict__ Q,
    float* __restrict__ cnt, int M)
{
    const int t  = threadIdx.x;
    const int ch = t & 127;
    const int rg = t >> 7;
    const int stride = gridDim.x * 2;

    float s0 = 0.f, s1 = 0.f, q = 0.f, c0 = 0.f, c1 = 0.f;
    for (int m = blockIdx.x * 2 + rg; m < M; m += stride) {
        const float x = out[(size_t)m * COUT + ch];
        const int b = batch_of_out[m];
        if (b == 0) s0 += x; else s1 += x;
        q += x * x;
        if (ch == 0) { if (b == 0) c0 += 1.f; else c1 += 1.f; }
    }
    atomicAdd(&S0[ch], s0);
    atomicAdd(&S1[ch], s1);
    atomicAdd(&Q[ch], q);
    if (ch == 0) {
        atomicAdd(&cnt[0], c0);
        atomicAdd(&cnt[1], c1);
    }
}

// ---------------------------------------------------------------------------
// Single-block: BN params (main + skip), SE MLP -> attn[2][128].
// ---------------------------------------------------------------------------
__global__ __launch_bounds__(128) void params_kernel(
    const float* __restrict__ S0, const float* __restrict__ S1,
    const float* __restrict__ Q,  const float* __restrict__ cnt,
    const float* __restrict__ skS, const float* __restrict__ skQ,
    const float* __restrict__ gamma, const float* __restrict__ beta,
    const float* __restrict__ sgamma, const float* __restrict__ sbeta,
    const float* __restrict__ fc1, const float* __restrict__ fc2,
    float* __restrict__ scale, float* __restrict__ shift,
    float* __restrict__ sscale, float* __restrict__ sshift,
    float* __restrict__ attn,
    int Ls)
{
    __shared__ float desc[2][COUT];
    __shared__ float hid[2][8];
    const int ch = threadIdx.x;

    const float c0 = cnt[0], c1 = cnt[1];
    const float Mf = c0 + c1;
    const float s0 = S0[ch], s1 = S1[ch];
    const float mu  = (s0 + s1) / Mf;
    const float var = Q[ch] / Mf - mu * mu;
    const float rs  = rsqrtf(var + 1e-5f);
    const float sc  = rs * gamma[ch];
    const float sh  = beta[ch] - mu * sc;
    scale[ch] = sc;
    shift[ch] = sh;
    desc[0][ch] = (s0 / c0) * sc + sh;
    desc[1][ch] = (s1 / c1) * sc + sh;

    const float lsf  = (float)Ls;
    const float mus  = skS[ch] / lsf;
    const float vars = skQ[ch] / lsf - mus * mus;
    const float rss  = rsqrtf(vars + 1e-5f);
    const float ssc  = rss * sgamma[ch];
    sscale[ch] = ssc;
    sshift[ch] = sbeta[ch] - mus * ssc;

    __syncthreads();
    if (ch < 16) {
        const int b = ch >> 3, h = ch & 7;
        float a = 0.f;
        for (int c = 0; c < COUT; ++c) a += desc[b][c] * fc1[c * 8 + h];
        hid[b][h] = fmaxf(a, 0.f);
    }
    __syncthreads();
    for (int b = 0; b < 2; ++b) {
        float a = 0.f;
        for (int h = 0; h < 8; ++h) a += hid[b][h] * fc2[h * COUT + ch];
        attn[b * COUT + ch] = 1.f / (1.f + expf(-a));
    }
}

// ---------------------------------------------------------------------------
// Epilogue: out = relu(bn(x)*attn[b] + bn_skip(G[inv])) in place.
// ---------------------------------------------------------------------------
__global__ __launch_bounds__(256) void final_kernel(
    float* __restrict__ out,
    const float* __restrict__ G,
    const int* __restrict__ inv_skip,
    const int* __restrict__ batch_of_out,
    const float* __restrict__ scale, const float* __restrict__ shift,
    const float* __restrict__ sscale, const float* __restrict__ sshift,
    const float* __restrict__ attn,
    int M)
{
    const int t  = threadIdx.x;
    const int ch = t & 127;
    const int rg = t >> 7;
    const float sc  = scale[ch],  sh  = shift[ch];
    const float ssc = sscale[ch], ssh = sshift[ch];
    const float a0 = attn[ch], a1 = attn[COUT + ch];
    const int stride = gridDim.x * 2;

    for (int m = blockIdx.x * 2 + rg; m < M; m += stride) {
        const float x = out[(size_t)m * COUT + ch];
        const int b = batch_of_out[m];
        const int j = inv_skip[m];
        float y = (x * sc + sh) * (b == 0 ? a0 : a1);
        float id = 0.f;
        if (j >= 0) id = G[(size_t)j * COUT + ch] * ssc + ssh;
        const float r = y + id;
        out[(size_t)m * COUT + ch] = r > 0.f ? r : 0.f;
    }
}

extern "C" void kernel_launch(void* const* d_in, const int* in_sizes, int n_in,
                              void* d_out, int out_size, void* d_ws, size_t ws_size,
                              hipStream_t stream)
{
    const float* feats  = (const float*)d_in[0];
    const float* Wc     = (const float*)d_in[1];
    const float* Wsk    = (const float*)d_in[2];
    const float* gamma  = (const float*)d_in[3];
    const float* beta   = (const float*)d_in[4];
    const float* sgamma = (const float*)d_in[5];
    const float* sbeta  = (const float*)d_in[6];
    const float* fc1    = (const float*)d_in[7];
    const float* fc2    = (const float*)d_in[8];
    const int* cin_idx  = (const int*)d_in[9];
    const int* cout_idx = (const int*)d_in[10];
    const int* sin_idx  = (const int*)d_in[11];
    const int* sout_idx = (const int*)d_in[12];
    const int* boo      = (const int*)d_in[13];

    const int N  = in_sizes[0] / CIN;
    const int P  = in_sizes[9] / 9;
    const int Ls = in_sizes[11];
    const int M  = in_sizes[13];

    float* out = (float*)d_out;

    // workspace layout
    char* ws = (char*)d_ws;
    float* G = (float*)ws;
    size_t off = (size_t)Ls * COUT * sizeof(float);
    int* inv_skip = (int*)(ws + off);
    off += (size_t)M * sizeof(int);
    off = (off + 255) & ~(size_t)255;
    float* stats = (float*)(ws + off);
    float* S0 = stats, *S1 = stats + 128, *Q = stats + 256;
    float* skS = stats + 384, *skQ = stats + 512, *cnt = stats + 640;
    float* params = stats + 704;   // scale,shift,sscale,sshift (4x128), attn (2x128)
    float* scale = params, *shift = params + 128;
    float* sscale = params + 256, *sshift = params + 384, *attn = params + 512;

    hipMemsetAsync(out, 0, (size_t)M * COUT * sizeof(float), stream);
    hipMemsetAsync(stats, 0, 704 * sizeof(float), stream);
    hipMemsetAsync(inv_skip, 0xFF, (size_t)M * sizeof(int), stream);  // -1

    conv_scatter_kernel<<<dim3(512, 9), 256, 0, stream>>>(
        feats, Wc, cin_idx, cout_idx, out, N, P);

    skip_kernel<<<dim3(256), 256, 0, stream>>>(
        feats, Wsk, sin_idx, sout_idx, G, inv_skip, skS, skQ, Ls);

    reduce_kernel<<<dim3(2048), 256, 0, stream>>>(
        out, boo, S0, S1, Q, cnt, M);

    params_kernel<<<1, 128, 0, stream>>>(
        S0, S1, Q, cnt, skS, skQ, gamma, beta, sgamma, sbeta, fc1, fc2,
        scale, shift, sscale, sshift, attn, Ls);

    final_kernel<<<2048, 256, 0, stream>>>(
        out, G, inv_skip, boo, scale, shift, sscale, sshift, attn, M);
}

// Round 2
// 519.604 us; speedup vs baseline: 1.9523x; 1.9523x over previous
//
#include <hip/hip_runtime.h>

#define CIN 64
#define COUT 128
#define TM 64   // output rows per conv tile

// ---------------------------------------------------------------------------
// Range table: lo_tab[k][t] = lower_bound(cout_idx[k], min(t*TM, M)).
// Padding entries have cout == M so they are never included.
// ---------------------------------------------------------------------------
__global__ __launch_bounds__(256) void range_kernel(
    const int* __restrict__ cout_idx, int* __restrict__ lo_tab,
    int ntiles, int M, int P)
{
    const int id = blockIdx.x * 256 + threadIdx.x;
    const int nt1 = ntiles + 1;
    if (id >= 9 * nt1) return;
    const int k = id / nt1;
    const int t = id - k * nt1;
    int target = t * TM; if (target > M) target = M;
    const int* __restrict__ c = cout_idx + (size_t)k * P;
    int lo = 0, hi = P;
    while (lo < hi) { const int mid = (lo + hi) >> 1; if (c[mid] < target) lo = mid + 1; else hi = mid; }
    lo_tab[(size_t)k * nt1 + t] = lo;
}

// ---------------------------------------------------------------------------
// Conv, output-tiled, no global atomics. Each block owns rows [m0, m0+TM).
// Weights in VGPRs; gathered feature row is wave-uniform -> SGPR loads.
// Fused BN partial stats in the epilogue.
// ---------------------------------------------------------------------------
__global__ __launch_bounds__(256, 2) void conv_tile_kernel(
    const float* __restrict__ feats,
    const float* __restrict__ Wc,
    const int* __restrict__ cin_idx,
    const int* __restrict__ cout_idx,
    const int* __restrict__ lo_tab,
    const int* __restrict__ boo,
    float* __restrict__ out,
    float* __restrict__ S0, float* __restrict__ S1, float* __restrict__ Q,
    int ntiles, int M, int P)
{
    __shared__ float acc[TM][COUT];
    __shared__ float red[256][3];
    const int t    = threadIdx.x;
    const int ch   = t & 127;
    const int rg   = t >> 7;              // 2 entry streams per block
    const int tile = blockIdx.x;
    const int m0   = tile * TM;
    const int nt1  = ntiles + 1;

    for (int r = rg; r < TM; r += 2) acc[r][ch] = 0.f;
    __syncthreads();

    for (int k = 0; k < 9; ++k) {
        const float* __restrict__ Wk = Wc + (size_t)k * CIN * COUT;
        float w[CIN];
#pragma unroll
        for (int i = 0; i < CIN; ++i) w[i] = Wk[i * COUT + ch];

        const int lo = lo_tab[(size_t)k * nt1 + tile];
        const int hi = lo_tab[(size_t)k * nt1 + tile + 1];
        const int* __restrict__ cik = cin_idx  + (size_t)k * P;
        const int* __restrict__ cok = cout_idx + (size_t)k * P;

        for (int e = lo + rg; e < hi; e += 2) {
            const int eu = __builtin_amdgcn_readfirstlane(e);
            const int ii = __builtin_amdgcn_readfirstlane(cik[eu]);
            const int oo = __builtin_amdgcn_readfirstlane(cok[eu]);
            const float* __restrict__ f = feats + (size_t)ii * CIN;
            float a0 = 0.f, a1 = 0.f, a2 = 0.f, a3 = 0.f;
#pragma unroll
            for (int i = 0; i < CIN; i += 4) {
                a0 = fmaf(f[i + 0], w[i + 0], a0);
                a1 = fmaf(f[i + 1], w[i + 1], a1);
                a2 = fmaf(f[i + 2], w[i + 2], a2);
                a3 = fmaf(f[i + 3], w[i + 3], a3);
            }
            atomicAdd(&acc[oo - m0][ch], (a0 + a1) + (a2 + a3));  // ds_add_f32
        }
    }
    __syncthreads();

    // write rows once + fused BN partial stats
    float s0 = 0.f, s1 = 0.f, q = 0.f;
    for (int r = rg; r < TM; r += 2) {
        const int m = m0 + r;
        if (m >= M) break;
        const float v = acc[r][ch];
        out[(size_t)m * COUT + ch] = v;
        if (boo[m]) s1 += v; else s0 += v;
        q += v * v;
    }
    red[t][0] = s0; red[t][1] = s1; red[t][2] = q;
    __syncthreads();
    if (t < 128) {
        atomicAdd(&S0[ch], red[t][0] + red[t + 128][0]);
        atomicAdd(&S1[ch], red[t][1] + red[t + 128][1]);
        atomicAdd(&Q[ch],  red[t][2] + red[t + 128][2]);
    }
}

// ---------------------------------------------------------------------------
// Skip path: G[e] = feats[sin_idx[e]] @ W_skip ; stats; inverse map.
// ---------------------------------------------------------------------------
__global__ __launch_bounds__(256, 2) void skip_kernel(
    const float* __restrict__ feats,
    const float* __restrict__ Ws,
    const int* __restrict__ sin_idx,
    const int* __restrict__ sout_idx,
    float* __restrict__ G,
    int* __restrict__ inv_skip,
    float* __restrict__ skS,
    float* __restrict__ skQ,
    int Ls)
{
    __shared__ float red[256][2];
    const int t    = threadIdx.x;
    const int ch   = t & 127;
    const int rg   = t >> 7;

    float w[CIN];
#pragma unroll
    for (int i = 0; i < CIN; ++i) w[i] = Ws[i * COUT + ch];

    const int stream_id = blockIdx.x * 2 + rg;
    const int nstreams  = gridDim.x * 2;

    float s1 = 0.f, s2 = 0.f;
    for (int e = stream_id; e < Ls; e += nstreams) {
        const int eu = __builtin_amdgcn_readfirstlane(e);
        const int ii = __builtin_amdgcn_readfirstlane(sin_idx[eu]);
        const int oo = __builtin_amdgcn_readfirstlane(sout_idx[eu]);
        const float* __restrict__ f = feats + (size_t)ii * CIN;
        float a0 = 0.f, a1 = 0.f, a2 = 0.f, a3 = 0.f;
#pragma unroll
        for (int i = 0; i < CIN; i += 4) {
            a0 = fmaf(f[i + 0], w[i + 0], a0);
            a1 = fmaf(f[i + 1], w[i + 1], a1);
            a2 = fmaf(f[i + 2], w[i + 2], a2);
            a3 = fmaf(f[i + 3], w[i + 3], a3);
        }
        const float acc = (a0 + a1) + (a2 + a3);
        G[(size_t)e * COUT + ch] = acc;
        s1 += acc;
        s2 += acc * acc;
        if (ch == 0) inv_skip[oo] = e;
    }
    red[t][0] = s1; red[t][1] = s2;
    __syncthreads();
    if (t < 128) {
        atomicAdd(&skS[ch], red[t][0] + red[t + 128][0]);
        atomicAdd(&skQ[ch], red[t][1] + red[t + 128][1]);
    }
}

// ---------------------------------------------------------------------------
// Single-block: BN params (main + skip), batch counts via bsearch, SE MLP.
// ---------------------------------------------------------------------------
__global__ __launch_bounds__(128) void params_kernel(
    const float* __restrict__ S0, const float* __restrict__ S1,
    const float* __restrict__ Q,
    const float* __restrict__ skS, const float* __restrict__ skQ,
    const int* __restrict__ boo,
    const float* __restrict__ gamma, const float* __restrict__ beta,
    const float* __restrict__ sgamma, const float* __restrict__ sbeta,
    const float* __restrict__ fc1, const float* __restrict__ fc2,
    float* __restrict__ scale, float* __restrict__ shift,
    float* __restrict__ sscale, float* __restrict__ sshift,
    float* __restrict__ attn,
    int Ls, int M)
{
    __shared__ float desc[2][COUT];
    __shared__ float hid[2][8];
    __shared__ float c0s;
    const int ch = threadIdx.x;

    if (ch == 0) {
        int lo = 0, hi = M;
        while (lo < hi) { const int mid = (lo + hi) >> 1; if (boo[mid] < 1) lo = mid + 1; else hi = mid; }
        c0s = (float)lo;
    }
    __syncthreads();
    const float c0 = c0s, c1 = (float)M - c0;
    const float Mf = (float)M;
    const float s0 = S0[ch], s1 = S1[ch];
    const float mu  = (s0 + s1) / Mf;
    const float var = Q[ch] / Mf - mu * mu;
    const float rs  = rsqrtf(var + 1e-5f);
    const float sc  = rs * gamma[ch];
    const float sh  = beta[ch] - mu * sc;
    scale[ch] = sc;
    shift[ch] = sh;
    desc[0][ch] = (s0 / c0) * sc + sh;
    desc[1][ch] = (s1 / c1) * sc + sh;

    const float lsf  = (float)Ls;
    const float mus  = skS[ch] / lsf;
    const float vars = skQ[ch] / lsf - mus * mus;
    const float rss  = rsqrtf(vars + 1e-5f);
    const float ssc  = rss * sgamma[ch];
    sscale[ch] = ssc;
    sshift[ch] = sbeta[ch] - mus * ssc;

    __syncthreads();
    if (ch < 16) {
        const int b = ch >> 3, h = ch & 7;
        float a = 0.f;
        for (int c = 0; c < COUT; ++c) a += desc[b][c] * fc1[c * 8 + h];
        hid[b][h] = fmaxf(a, 0.f);
    }
    __syncthreads();
    for (int b = 0; b < 2; ++b) {
        float a = 0.f;
        for (int h = 0; h < 8; ++h) a += hid[b][h] * fc2[h * COUT + ch];
        attn[b * COUT + ch] = 1.f / (1.f + expf(-a));
    }
}

// ---------------------------------------------------------------------------
// Epilogue: out = relu(bn(x)*attn[b] + bn_skip(G[inv])), float4-vectorized.
// ---------------------------------------------------------------------------
__global__ __launch_bounds__(256) void final_kernel(
    float* __restrict__ out,
    const float* __restrict__ G,
    const int* __restrict__ inv_skip,
    const int* __restrict__ batch_of_out,
    const float* __restrict__ scale, const float* __restrict__ shift,
    const float* __restrict__ sscale, const float* __restrict__ sshift,
    const float* __restrict__ attn,
    int M)
{
    const int t  = threadIdx.x;
    const int c4 = (t & 31) * 4;
    const int rw = t >> 5;                // 8 rows per block-iter
    const float4 sc  = *(const float4*)&scale[c4];
    const float4 sh  = *(const float4*)&shift[c4];
    const float4 ssc = *(const float4*)&sscale[c4];
    const float4 ssh = *(const float4*)&sshift[c4];
    const float4 at0 = *(const float4*)&attn[c4];
    const float4 at1 = *(const float4*)&attn[COUT + c4];

    for (int m = blockIdx.x * 8 + rw; m < M; m += gridDim.x * 8) {
        const float4 x = *(const float4*)&out[(size_t)m * COUT + c4];
        const int b = batch_of_out[m];
        const int j = inv_skip[m];
        const float4 av = b ? at1 : at0;
        float4 y;
        y.x = (x.x * sc.x + sh.x) * av.x;
        y.y = (x.y * sc.y + sh.y) * av.y;
        y.z = (x.z * sc.z + sh.z) * av.z;
        y.w = (x.w * sc.w + sh.w) * av.w;
        if (j >= 0) {
            const float4 g = *(const float4*)&G[(size_t)j * COUT + c4];
            y.x += g.x * ssc.x + ssh.x;
            y.y += g.y * ssc.y + ssh.y;
            y.z += g.z * ssc.z + ssh.z;
            y.w += g.w * ssc.w + ssh.w;
        }
        y.x = y.x > 0.f ? y.x : 0.f;
        y.y = y.y > 0.f ? y.y : 0.f;
        y.z = y.z > 0.f ? y.z : 0.f;
        y.w = y.w > 0.f ? y.w : 0.f;
        *(float4*)&out[(size_t)m * COUT + c4] = y;
    }
}

extern "C" void kernel_launch(void* const* d_in, const int* in_sizes, int n_in,
                              void* d_out, int out_size, void* d_ws, size_t ws_size,
                              hipStream_t stream)
{
    const float* feats  = (const float*)d_in[0];
    const float* Wc     = (const float*)d_in[1];
    const float* Wsk    = (const float*)d_in[2];
    const float* gamma  = (const float*)d_in[3];
    const float* beta   = (const float*)d_in[4];
    const float* sgamma = (const float*)d_in[5];
    const float* sbeta  = (const float*)d_in[6];
    const float* fc1    = (const float*)d_in[7];
    const float* fc2    = (const float*)d_in[8];
    const int* cin_idx  = (const int*)d_in[9];
    const int* cout_idx = (const int*)d_in[10];
    const int* sin_idx  = (const int*)d_in[11];
    const int* sout_idx = (const int*)d_in[12];
    const int* boo      = (const int*)d_in[13];

    const int P  = in_sizes[9] / 9;
    const int Ls = in_sizes[11];
    const int M  = in_sizes[13];
    const int ntiles = (M + TM - 1) / TM;

    float* out = (float*)d_out;

    // workspace layout
    char* ws = (char*)d_ws;
    float* G = (float*)ws;
    size_t off = (size_t)Ls * COUT * sizeof(float);
    int* inv_skip = (int*)(ws + off);
    off += (size_t)M * sizeof(int);
    off = (off + 255) & ~(size_t)255;
    int* lo_tab = (int*)(ws + off);
    off += (size_t)9 * (ntiles + 1) * sizeof(int);
    off = (off + 255) & ~(size_t)255;
    float* stats = (float*)(ws + off);
    float* S0 = stats, *S1 = stats + 128, *Q = stats + 256;
    float* skS = stats + 384, *skQ = stats + 512;
    float* params = stats + 704;
    float* scale = params, *shift = params + 128;
    float* sscale = params + 256, *sshift = params + 384, *attn = params + 512;

    hipMemsetAsync(stats, 0, 704 * sizeof(float), stream);
    hipMemsetAsync(inv_skip, 0xFF, (size_t)M * sizeof(int), stream);  // -1

    const int nrange = 9 * (ntiles + 1);
    range_kernel<<<(nrange + 255) / 256, 256, 0, stream>>>(cout_idx, lo_tab, ntiles, M, P);

    conv_tile_kernel<<<ntiles, 256, 0, stream>>>(
        feats, Wc, cin_idx, cout_idx, lo_tab, boo, out, S0, S1, Q, ntiles, M, P);

    skip_kernel<<<1024, 256, 0, stream>>>(
        feats, Wsk, sin_idx, sout_idx, G, inv_skip, skS, skQ, Ls);

    params_kernel<<<1, 128, 0, stream>>>(
        S0, S1, Q, skS, skQ, boo, gamma, beta, sgamma, sbeta, fc1, fc2,
        scale, shift, sscale, sshift, attn, Ls, M);

    final_kernel<<<2048, 256, 0, stream>>>(
        out, G, inv_skip, boo, scale, shift, sscale, sshift, attn, M);
}